// Round 11
// baseline (242.412 us; speedup 1.0000x reference)
//
#include <hip/hip_runtime.h>

typedef unsigned short u16;
typedef __attribute__((ext_vector_type(8))) __bf16 bf16x8;
typedef __attribute__((ext_vector_type(4))) float f32x4;

#define NB 2
#define NT 2048
#define ND 1024
#define NH 16
#define HD 64

__device__ __forceinline__ float b2f(u16 u) {
  union { float f; unsigned int i; } v; v.i = ((unsigned int)u) << 16; return v.f;
}
__device__ __forceinline__ u16 f2b(float f) {
  union { float f; unsigned int i; } v; v.f = f;
  unsigned int r = (v.i + 0x7FFFu + ((v.i >> 16) & 1u)) >> 16;
  return (u16)r;
}

__device__ __forceinline__ void gload_lds16(const u16* g, u16* lds) {
  __builtin_amdgcn_global_load_lds(
      (const __attribute__((address_space(1))) unsigned int*)(g),
      (__attribute__((address_space(3))) unsigned int*)(lds),
      16, 0, 0);
}

__device__ __forceinline__ f32x4 mfma16(bf16x8 a, bf16x8 b, f32x4 c) {
  return __builtin_amdgcn_mfma_f32_16x16x32_bf16(a, b, c, 0, 0, 0);
}

// DPP row_ror<N>: 16-lane-domain reduction at VALU latency (no ds_swizzle).
template <int N>
__device__ __forceinline__ float ror16(float x) {
  return __int_as_float(__builtin_amdgcn_update_dpp(
      __float_as_int(x), __float_as_int(x), 0x120 | N, 0xF, 0xF, true));
}
__device__ __forceinline__ float rsum16(float x) {
  x += ror16<8>(x);
  x += ror16<4>(x);
  x += ror16<2>(x);
  x += ror16<1>(x);
  return x;
}

// Fast sin/cos: radians -> revolutions, fract range-reduce, v_sin/v_cos.
__device__ __forceinline__ float fast_sin(float a) {
  float r = a * 0.15915494309189535f;
  r -= floorf(r);
  return __builtin_amdgcn_sinf(r);
}
__device__ __forceinline__ float fast_cos(float a) {
  float r = a * 0.15915494309189535f;
  r -= floorf(r);
  return __builtin_amdgcn_cosf(r);
}

// ---------------- cast: f32 -> bf16, 8 elems/thread -------------------------
__global__ __launch_bounds__(256) void cast_f32_bf16(const float* __restrict__ in,
                                                     u16* __restrict__ out, int n) {
  int i = (blockIdx.x * 256 + threadIdx.x) * 8;
  if (i + 8 <= n) {
#pragma unroll
    for (int j = 0; j < 8; ++j) out[i + j] = f2b(in[i + j]);
  }
}

// ------------- weight transpose+cast: in f32 (K x N) -> out bf16 (N x K) ----
__global__ __launch_bounds__(256) void transpose_cast(const float* __restrict__ in,
                                                      u16* __restrict__ out,
                                                      int K, int N) {
  __shared__ u16 tile[32][33];
  int n0 = blockIdx.x * 32, k0 = blockIdx.y * 32;
  int tx = threadIdx.x, ty = threadIdx.y;
  for (int i = ty; i < 32; i += 8)
    tile[i][tx] = f2b(in[(size_t)(k0 + i) * N + n0 + tx]);
  __syncthreads();
  for (int i = ty; i < 32; i += 8)
    out[(size_t)(n0 + i) * K + k0 + tx] = tile[tx][i];
}

// ------- GEMM: C(MxN) = A(MxK) * Bt(NxK)^T + bias(f32); out bf16 or f32 -----
// R8-proven config: BK=32, no block remap (R10's BK=64 + XCD remap regressed).
template <int BM, bool F32OUT>
__global__ __launch_bounds__(256) void gemm_bt(const u16* __restrict__ A,
                                               const u16* __restrict__ Bt,
                                               const float* __restrict__ bias,
                                               void* __restrict__ Cv,
                                               int M, int N, int K) {
  constexpr int MI = BM / 32;
  __shared__ alignas(16) u16 As[BM * 32];
  __shared__ alignas(16) u16 Bs[128 * 32];
  const int tid = threadIdx.x;
  const int lane = tid & 63;
  const int wave = tid >> 6;
  const int l15 = lane & 15, quad = lane >> 4;
  const int wm = (wave >> 1) * (BM / 2), wn = (wave & 1) * 64;
  const int row0 = blockIdx.y * BM, col0 = blockIdx.x * 128;

  f32x4 acc[MI][4] = {};

  for (int k0 = 0; k0 < K; k0 += 32) {
    __syncthreads();
#pragma unroll
    for (int p = 0; p < BM / 64; ++p) {
      int idx8 = p * 256 + tid;
      int r = idx8 >> 2, c = (idx8 & 3) * 8;
      gload_lds16(&A[(size_t)(row0 + r) * K + k0 + c], &As[idx8 * 8]);
    }
#pragma unroll
    for (int p = 0; p < 2; ++p) {
      int idx8 = p * 256 + tid;
      int r = idx8 >> 2, c = (idx8 & 3) * 8;
      gload_lds16(&Bt[(size_t)(col0 + r) * K + k0 + c], &Bs[idx8 * 8]);
    }
    __syncthreads();
    bf16x8 af[MI], bfr[4];
#pragma unroll
    for (int mi = 0; mi < MI; ++mi)
      af[mi] = *(const bf16x8*)&As[(wm + mi * 16 + l15) * 32 + quad * 8];
#pragma unroll
    for (int ni = 0; ni < 4; ++ni)
      bfr[ni] = *(const bf16x8*)&Bs[(wn + ni * 16 + l15) * 32 + quad * 8];
#pragma unroll
    for (int mi = 0; mi < MI; ++mi)
#pragma unroll
      for (int ni = 0; ni < 4; ++ni)
        acc[mi][ni] = mfma16(af[mi], bfr[ni], acc[mi][ni]);
  }

#pragma unroll
  for (int ni = 0; ni < 4; ++ni) {
    int c = col0 + wn + ni * 16 + l15;
    float bv = bias[c];
#pragma unroll
    for (int mi = 0; mi < MI; ++mi) {
      int r0 = row0 + wm + mi * 16 + quad * 4;
      f32x4 v = acc[mi][ni];
#pragma unroll
      for (int r = 0; r < 4; ++r) {
        if (F32OUT)
          ((float*)Cv)[(size_t)(r0 + r) * N + c] = v[r] + bv;
        else
          ((u16*)Cv)[(size_t)(r0 + r) * N + c] = f2b(v[r] + bv);
      }
    }
  }
}

// ------- Fused RoPE(q,k) + V swizzle into MFMA-fragment layouts -------------
// Q carries the 0.125 attention scale (exact pow2; R8-proven numerics).
__global__ __launch_bounds__(256) void prep_frag(const u16* __restrict__ qkv,
                                                 u16* __restrict__ qsw,
                                                 u16* __restrict__ ksw,
                                                 u16* __restrict__ vsw) {
  __shared__ u16 tq[32 * 72];
  __shared__ u16 tk[32 * 72];
  __shared__ u16 tv[32 * 72];
  const int bh = blockIdx.y;
  const int b = bh >> 4, h = bh & 15;
  const int t0 = blockIdx.x * 32;
  const int tid = threadIdx.x;

  {
    int row = tid >> 3, col = (tid & 7) * 8;
    const u16* src = &qkv[(size_t)(b * NT + t0 + row) * 3072 + h * HD + col];
    *(bf16x8*)&tq[row * 72 + col] = *(const bf16x8*)src;
    *(bf16x8*)&tk[row * 72 + col] = *(const bf16x8*)(src + ND);
    *(bf16x8*)&tv[row * 72 + col] = *(const bf16x8*)(src + 2 * ND);
  }
  __syncthreads();

  // --- rope phase (q | k split across waves) ---
  {
    const int isK = tid >> 7;          // wave-uniform
    const int chunk = (tid >> 4) & 7;  // ks*4+quad
    const int tl = tid & 15;
    const int ks = chunk >> 2, quad = chunk & 3;
    const u16* tile = isK ? tk : tq;
    u16* dst = isK ? ksw : qsw;
    const float scale = isK ? 1.0f : 0.125f;
    const float LOG1E4 = 9.210340371976184f;

#pragma unroll
    for (int rbloc = 0; rbloc < 2; ++rbloc) {
      const int row = rbloc * 16 + tl;
      const float tf = (float)(t0 + row);
      union { u16 s[8]; bf16x8 v; } o;
#pragma unroll
      for (int e = 0; e < 8; ++e) {
        int c = ks * 32 + quad * 8 + e;
        int j = c & 31;
        int c1 = 2 * j, c2 = 2 * j + 1;
        float inv1 = __expf(-((float)(c1 & 31)) * (1.0f / 32.0f) * LOG1E4);
        float inv2 = __expf(-((float)(c2 & 31)) * (1.0f / 32.0f) * LOG1E4);
        float a1 = tf * inv1, a2 = tf * inv2;
        float sA = (c1 < 32) ? fast_sin(a1) : fast_cos(a1);
        float cA = (c2 < 32) ? fast_sin(a2) : fast_cos(a2);
        float x1 = b2f(tile[row * 72 + c1]), x2 = b2f(tile[row * 72 + c2]);
        float ov = (c < 32) ? (x1 * cA - x2 * sA) : (x1 * sA + x2 * cA);
        o.s[e] = f2b(ov * scale);
      }
      size_t addr =
          ((((size_t)bh * 128 + (t0 >> 4) + rbloc) * 2 + ks) * 64 + quad * 16 + tl) * 8;
      *(bf16x8*)&dst[addr] = o.v;
    }
  }

  // --- v swizzle phase (reads tv only; no extra sync needed) ---
  {
    const int ni = tid >> 6, lane = tid & 63;
    const int quad = lane >> 4, l15 = lane & 15;
    union { u16 s[8]; bf16x8 v; } o;
#pragma unroll
    for (int e = 0; e < 8; ++e)
      o.s[e] = tv[(quad * 8 + e) * 72 + ni * 16 + l15];
    *(bf16x8*)&vsw[(((size_t)bh * 64 + (t0 >> 5)) * 4 + ni) * 512 + lane * 8] = o.v;
  }
}

// ---------------- Flash attention v8 ----------------------------------------
// Exactly R8's v5 (50.4us: __expf, DPP rsum, RNE f2b) with ONE change:
// batched register prefetch. All 16 K-frags load in one burst before the QK
// MFMAs (one ~400cyc L2 round-trip instead of 16 serialized), and all 16
// V-frags load before the softmax phase (latency hides under exp/P-store).
// R7/R8/R10 counters localized the bottleneck to serialized kf L2 trips:
// per-iter serial 6.8k cyc == 16 loads x ~400cyc; R7's 8 loads == 3.7k.
__global__ __launch_bounds__(128, 3) void flash_kernel(const u16* __restrict__ qsw,
                                                       const u16* __restrict__ ksw,
                                                       const u16* __restrict__ vsw,
                                                       u16* __restrict__ attn) {
  __shared__ alignas(16) u16 Ps[2 * 5120];  // per-wave [ks32][32 rows][40] 10KB
  __shared__ float Ll[32];

  const int tid = threadIdx.x;
  const int w = tid >> 6;
  const int lane = tid & 63;
  const int l15 = lane & 15, quad = lane >> 4;
  const int linear = (int)blockIdx.x;
  const int bh = linear & 31;         // head-major: L2 locality
  const int qt = 63 - (linear >> 5);  // 32-row tile, big first
  const int r0 = qt * 32;
  u16* Psw = &Ps[w * 5120];

  bf16x8 aq[2][2];
#pragma unroll
  for (int mi = 0; mi < 2; ++mi)
#pragma unroll
    for (int ks = 0; ks < 2; ++ks)
      aq[mi][ks] = *(const bf16x8*)&qsw[
          ((((size_t)bh * 128 + qt * 2 + mi) * 2 + ks) * 64 + lane) * 8];

  f32x4 oacc[2][4] = {};
  float lst[8] = {0.f, 0.f, 0.f, 0.f, 0.f, 0.f, 0.f, 0.f};

  const int ktmax = qt >> 2;
  for (int kt = w; kt <= ktmax; kt += 2) {
    // Batched K-fragment loads: 16 independent 1KB reads in flight at once.
    bf16x8 kf[2][8];
#pragma unroll
    for (int ks = 0; ks < 2; ++ks)
#pragma unroll
      for (int ni = 0; ni < 8; ++ni)
        kf[ks][ni] = *(const bf16x8*)&ksw[
            ((((size_t)bh * 128 + kt * 8 + ni) * 2 + ks) * 64 + lane) * 8];

    // S = Q K^T (scale pre-folded into Q)
    f32x4 sacc[2][8] = {};
#pragma unroll
    for (int ks = 0; ks < 2; ++ks)
#pragma unroll
      for (int ni = 0; ni < 8; ++ni) {
        sacc[0][ni] = mfma16(aq[0][ks], kf[ks][ni], sacc[0][ni]);
        sacc[1][ni] = mfma16(aq[1][ks], kf[ks][ni], sacc[1][ni]);
      }

    // Batched V-fragment loads: issued now so their L2 latency is covered by
    // the entire softmax phase below.
    bf16x8 vf[4][4];
#pragma unroll
    for (int ks = 0; ks < 4; ++ks)
#pragma unroll
      for (int ni = 0; ni < 4; ++ni)
        vf[ks][ni] = *(const bf16x8*)&vsw[
            (((size_t)bh * 64 + kt * 4 + ks) * 4 + ni) * 512 + lane * 8];

    const bool diag = (kt == ktmax);
    const int k0 = kt * 128;
#pragma unroll
    for (int mi = 0; mi < 2; ++mi)
#pragma unroll
      for (int r = 0; r < 4; ++r) {
        const int prow = mi * 16 + quad * 4 + r;
        float sv[8];
#pragma unroll
        for (int ni = 0; ni < 8; ++ni) sv[ni] = sacc[mi][ni][r];
        if (diag) {
#pragma unroll
          for (int ni = 0; ni < 8; ++ni)
            if (k0 + ni * 16 + l15 > r0 + prow) sv[ni] = -__builtin_inff();
        }
        float rs = 0.f;
#pragma unroll
        for (int ni = 0; ni < 8; ++ni) {
          float p = __expf(sv[ni]);
          sv[ni] = p;
          rs += p;
        }
        lst[mi * 4 + r] += rsum16(rs);
#pragma unroll
        for (int ni = 0; ni < 8; ++ni)
          Psw[(ni >> 1) * 1280 + prow * 40 + (ni & 1) * 16 + l15] = f2b(sv[ni]);
      }

    // Wave-private LDS RAW: pin source order (TBAA could hoist the reads).
    asm volatile("" ::: "memory");

#pragma unroll
    for (int ks = 0; ks < 4; ++ks) {
      bf16x8 ap0 = *(const bf16x8*)&Psw[ks * 1280 + l15 * 40 + quad * 8];
      bf16x8 ap1 = *(const bf16x8*)&Psw[ks * 1280 + (16 + l15) * 40 + quad * 8];
#pragma unroll
      for (int ni = 0; ni < 4; ++ni) {
        oacc[0][ni] = mfma16(ap0, vf[ks][ni], oacc[0][ni]);
        oacc[1][ni] = mfma16(ap1, vf[ks][ni], oacc[1][ni]);
      }
    }
  }

  // Static-max merge: partial (O, l) just add. Wave1 publishes via its own
  // (now dead) Ps region; __syncthreads orders the cross-type LDS reuse.
  float* Of = (float*)&Ps[5120];  // 8KB needed, 10KB available
  if (w == 1) {
#pragma unroll
    for (int mi = 0; mi < 2; ++mi)
#pragma unroll
      for (int r = 0; r < 4; ++r) {
        const int row = mi * 16 + quad * 4 + r;
        if (l15 == 0) Ll[row] = lst[mi * 4 + r];
#pragma unroll
        for (int ni = 0; ni < 4; ++ni)
          Of[row * 64 + ni * 16 + l15] = oacc[mi][ni][r];
      }
  }
  __syncthreads();
  if (w == 0) {
    const int b = bh >> 4, h = bh & 15;
#pragma unroll
    for (int mi = 0; mi < 2; ++mi)
#pragma unroll
      for (int r = 0; r < 4; ++r) {
        const int row = mi * 16 + quad * 4 + r;
        const float rl = 1.0f / (lst[mi * 4 + r] + Ll[row]);
        const int trow = r0 + row;
#pragma unroll
        for (int ni = 0; ni < 4; ++ni) {
          float o = oacc[mi][ni][r] + Of[row * 64 + ni * 16 + l15];
          attn[((size_t)b * NT + trow) * ND + h * HD + ni * 16 + l15] = f2b(o * rl);
        }
      }
  }
}

extern "C" void kernel_launch(void* const* d_in, const int* in_sizes, int n_in,
                              void* d_out, int out_size, void* d_ws, size_t ws_size,
                              hipStream_t stream) {
  const float* x = (const float*)d_in[0];      // (B,T,D) f32
  const float* qkv_w = (const float*)d_in[1];  // (D,3D) f32
  const float* qkv_b = (const float*)d_in[2];  // (3D,) f32
  const float* out_w = (const float*)d_in[3];  // (D,D) f32
  const float* out_b = (const float*)d_in[4];  // (D,) f32
  float* out = (float*)d_out;

  u16* ws = (u16*)d_ws;
  u16* xb    = ws;                          // 4096*1024
  u16* wqkvT = xb + (size_t)4096 * 1024;    // 3072*1024
  u16* woutT = wqkvT + 3072 * 1024;         // 1024*1024
  u16* qkv   = woutT + 1024 * 1024;         // 4096*3072
  u16* qsw   = qkv + (size_t)4096 * 3072;   // 32*2048*64
  u16* ksw   = qsw + (size_t)32 * 2048 * 64;
  u16* vsw   = ksw + (size_t)32 * 2048 * 64;
  u16* attn  = vsw + (size_t)32 * 2048 * 64; // 4096*1024

  cast_f32_bf16<<<(NB * NT * ND) / (256 * 8), 256, 0, stream>>>(
      x, xb, NB * NT * ND);

  transpose_cast<<<dim3(3 * ND / 32, ND / 32), dim3(32, 8), 0, stream>>>(
      qkv_w, wqkvT, ND, 3 * ND);
  transpose_cast<<<dim3(ND / 32, ND / 32), dim3(32, 8), 0, stream>>>(
      out_w, woutT, ND, ND);

  gemm_bt<128, false><<<dim3(3 * ND / 128, NB * NT / 128), 256, 0, stream>>>(
      xb, wqkvT, qkv_b, qkv, NB * NT, 3 * ND, ND);

  prep_frag<<<dim3(NT / 32, NB * NH), 256, 0, stream>>>(qkv, qsw, ksw, vsw);

  flash_kernel<<<dim3(2048), 128, 0, stream>>>(qsw, ksw, vsw, attn);

  gemm_bt<64, true><<<dim3(ND / 128, NB * NT / 64), 256, 0, stream>>>(
      attn, woutT, out_b, out, NB * NT, ND, ND);
}

// Round 12
// 195.111 us; speedup vs baseline: 1.2424x; 1.2424x over previous
//
#include <hip/hip_runtime.h>

typedef unsigned short u16;
typedef __attribute__((ext_vector_type(8))) __bf16 bf16x8;
typedef __attribute__((ext_vector_type(4))) float f32x4;

#define NB 2
#define NT 2048
#define ND 1024
#define NH 16
#define HD 64

__device__ __forceinline__ float b2f(u16 u) {
  union { float f; unsigned int i; } v; v.i = ((unsigned int)u) << 16; return v.f;
}
__device__ __forceinline__ u16 f2b(float f) {
  union { float f; unsigned int i; } v; v.f = f;
  unsigned int r = (v.i + 0x7FFFu + ((v.i >> 16) & 1u)) >> 16;
  return (u16)r;
}

__device__ __forceinline__ void gload_lds16(const u16* g, u16* lds) {
  __builtin_amdgcn_global_load_lds(
      (const __attribute__((address_space(1))) unsigned int*)(g),
      (__attribute__((address_space(3))) unsigned int*)(lds),
      16, 0, 0);
}

__device__ __forceinline__ f32x4 mfma16(bf16x8 a, bf16x8 b, f32x4 c) {
  return __builtin_amdgcn_mfma_f32_16x16x32_bf16(a, b, c, 0, 0, 0);
}

// DPP row_ror<N>: 16-lane-domain reduction at VALU latency (no ds_swizzle).
template <int N>
__device__ __forceinline__ float ror16(float x) {
  return __int_as_float(__builtin_amdgcn_update_dpp(
      __float_as_int(x), __float_as_int(x), 0x120 | N, 0xF, 0xF, true));
}
__device__ __forceinline__ float rsum16(float x) {
  x += ror16<8>(x);
  x += ror16<4>(x);
  x += ror16<2>(x);
  x += ror16<1>(x);
  return x;
}

// Fast sin/cos: radians -> revolutions, fract range-reduce, v_sin/v_cos.
__device__ __forceinline__ float fast_sin(float a) {
  float r = a * 0.15915494309189535f;
  r -= floorf(r);
  return __builtin_amdgcn_sinf(r);
}
__device__ __forceinline__ float fast_cos(float a) {
  float r = a * 0.15915494309189535f;
  r -= floorf(r);
  return __builtin_amdgcn_cosf(r);
}

// ---------------- cast: f32 -> bf16, 8 elems/thread -------------------------
__global__ __launch_bounds__(256) void cast_f32_bf16(const float* __restrict__ in,
                                                     u16* __restrict__ out, int n) {
  int i = (blockIdx.x * 256 + threadIdx.x) * 8;
  if (i + 8 <= n) {
#pragma unroll
    for (int j = 0; j < 8; ++j) out[i + j] = f2b(in[i + j]);
  }
}

// ------------- weight transpose+cast: in f32 (K x N) -> out bf16 (N x K) ----
__global__ __launch_bounds__(256) void transpose_cast(const float* __restrict__ in,
                                                      u16* __restrict__ out,
                                                      int K, int N) {
  __shared__ u16 tile[32][33];
  int n0 = blockIdx.x * 32, k0 = blockIdx.y * 32;
  int tx = threadIdx.x, ty = threadIdx.y;
  for (int i = ty; i < 32; i += 8)
    tile[i][tx] = f2b(in[(size_t)(k0 + i) * N + n0 + tx]);
  __syncthreads();
  for (int i = ty; i < 32; i += 8)
    out[(size_t)(n0 + i) * K + k0 + tx] = tile[tx][i];
}

// ------- GEMM: C(MxN) = A(MxK) * Bt(NxK)^T + bias(f32); out bf16 or f32 -----
// R8-proven config: BK=32, no block remap.
template <int BM, bool F32OUT>
__global__ __launch_bounds__(256) void gemm_bt(const u16* __restrict__ A,
                                               const u16* __restrict__ Bt,
                                               const float* __restrict__ bias,
                                               void* __restrict__ Cv,
                                               int M, int N, int K) {
  constexpr int MI = BM / 32;
  __shared__ alignas(16) u16 As[BM * 32];
  __shared__ alignas(16) u16 Bs[128 * 32];
  const int tid = threadIdx.x;
  const int lane = tid & 63;
  const int wave = tid >> 6;
  const int l15 = lane & 15, quad = lane >> 4;
  const int wm = (wave >> 1) * (BM / 2), wn = (wave & 1) * 64;
  const int row0 = blockIdx.y * BM, col0 = blockIdx.x * 128;

  f32x4 acc[MI][4] = {};

  for (int k0 = 0; k0 < K; k0 += 32) {
    __syncthreads();
#pragma unroll
    for (int p = 0; p < BM / 64; ++p) {
      int idx8 = p * 256 + tid;
      int r = idx8 >> 2, c = (idx8 & 3) * 8;
      gload_lds16(&A[(size_t)(row0 + r) * K + k0 + c], &As[idx8 * 8]);
    }
#pragma unroll
    for (int p = 0; p < 2; ++p) {
      int idx8 = p * 256 + tid;
      int r = idx8 >> 2, c = (idx8 & 3) * 8;
      gload_lds16(&Bt[(size_t)(col0 + r) * K + k0 + c], &Bs[idx8 * 8]);
    }
    __syncthreads();
    bf16x8 af[MI], bfr[4];
#pragma unroll
    for (int mi = 0; mi < MI; ++mi)
      af[mi] = *(const bf16x8*)&As[(wm + mi * 16 + l15) * 32 + quad * 8];
#pragma unroll
    for (int ni = 0; ni < 4; ++ni)
      bfr[ni] = *(const bf16x8*)&Bs[(wn + ni * 16 + l15) * 32 + quad * 8];
#pragma unroll
    for (int mi = 0; mi < MI; ++mi)
#pragma unroll
      for (int ni = 0; ni < 4; ++ni)
        acc[mi][ni] = mfma16(af[mi], bfr[ni], acc[mi][ni]);
  }

#pragma unroll
  for (int ni = 0; ni < 4; ++ni) {
    int c = col0 + wn + ni * 16 + l15;
    float bv = bias[c];
#pragma unroll
    for (int mi = 0; mi < MI; ++mi) {
      int r0 = row0 + wm + mi * 16 + quad * 4;
      f32x4 v = acc[mi][ni];
#pragma unroll
      for (int r = 0; r < 4; ++r) {
        if (F32OUT)
          ((float*)Cv)[(size_t)(r0 + r) * N + c] = v[r] + bv;
        else
          ((u16*)Cv)[(size_t)(r0 + r) * N + c] = f2b(v[r] + bv);
      }
    }
  }
}

// ------- Fused RoPE(q,k) + V swizzle into MFMA-fragment layouts -------------
// Q carries the 0.125 attention scale (exact pow2; R8-proven numerics).
__global__ __launch_bounds__(256) void prep_frag(const u16* __restrict__ qkv,
                                                 u16* __restrict__ qsw,
                                                 u16* __restrict__ ksw,
                                                 u16* __restrict__ vsw) {
  __shared__ u16 tq[32 * 72];
  __shared__ u16 tk[32 * 72];
  __shared__ u16 tv[32 * 72];
  const int bh = blockIdx.y;
  const int b = bh >> 4, h = bh & 15;
  const int t0 = blockIdx.x * 32;
  const int tid = threadIdx.x;

  {
    int row = tid >> 3, col = (tid & 7) * 8;
    const u16* src = &qkv[(size_t)(b * NT + t0 + row) * 3072 + h * HD + col];
    *(bf16x8*)&tq[row * 72 + col] = *(const bf16x8*)src;
    *(bf16x8*)&tk[row * 72 + col] = *(const bf16x8*)(src + ND);
    *(bf16x8*)&tv[row * 72 + col] = *(const bf16x8*)(src + 2 * ND);
  }
  __syncthreads();

  // --- rope phase (q | k split across waves) ---
  {
    const int isK = tid >> 7;          // wave-uniform
    const int chunk = (tid >> 4) & 7;  // ks*4+quad
    const int tl = tid & 15;
    const int ks = chunk >> 2, quad = chunk & 3;
    const u16* tile = isK ? tk : tq;
    u16* dst = isK ? ksw : qsw;
    const float scale = isK ? 1.0f : 0.125f;
    const float LOG1E4 = 9.210340371976184f;

#pragma unroll
    for (int rbloc = 0; rbloc < 2; ++rbloc) {
      const int row = rbloc * 16 + tl;
      const float tf = (float)(t0 + row);
      union { u16 s[8]; bf16x8 v; } o;
#pragma unroll
      for (int e = 0; e < 8; ++e) {
        int c = ks * 32 + quad * 8 + e;
        int j = c & 31;
        int c1 = 2 * j, c2 = 2 * j + 1;
        float inv1 = __expf(-((float)(c1 & 31)) * (1.0f / 32.0f) * LOG1E4);
        float inv2 = __expf(-((float)(c2 & 31)) * (1.0f / 32.0f) * LOG1E4);
        float a1 = tf * inv1, a2 = tf * inv2;
        float sA = (c1 < 32) ? fast_sin(a1) : fast_cos(a1);
        float cA = (c2 < 32) ? fast_sin(a2) : fast_cos(a2);
        float x1 = b2f(tile[row * 72 + c1]), x2 = b2f(tile[row * 72 + c2]);
        float ov = (c < 32) ? (x1 * cA - x2 * sA) : (x1 * sA + x2 * cA);
        o.s[e] = f2b(ov * scale);
      }
      size_t addr =
          ((((size_t)bh * 128 + (t0 >> 4) + rbloc) * 2 + ks) * 64 + quad * 16 + tl) * 8;
      *(bf16x8*)&dst[addr] = o.v;
    }
  }

  // --- v swizzle phase (reads tv only; no extra sync needed) ---
  {
    const int ni = tid >> 6, lane = tid & 63;
    const int quad = lane >> 4, l15 = lane & 15;
    union { u16 s[8]; bf16x8 v; } o;
#pragma unroll
    for (int e = 0; e < 8; ++e)
      o.s[e] = tv[(quad * 8 + e) * 72 + ni * 16 + l15];
    *(bf16x8*)&vsw[(((size_t)bh * 64 + (t0 >> 5)) * 4 + ni) * 512 + lane * 8] = o.v;
  }
}

// ---------------- Flash attention v9 ----------------------------------------
// R11's batched-prefetch structure, with the spill fixed: __launch_bounds__
// (128, 2) -> 256 unified regs/wave. R11's (128,3) capped at ~170 while the
// batch needs ~200-240 peak -> the "register" prefetch spilled to scratch
// (WRITE_SIZE 11->226 MB, the entire regression). Measured occupancy was
// already ~2 waves/SIMD, so the declared cap costs nothing.
__global__ __launch_bounds__(128, 2) void flash_kernel(const u16* __restrict__ qsw,
                                                       const u16* __restrict__ ksw,
                                                       const u16* __restrict__ vsw,
                                                       u16* __restrict__ attn) {
  __shared__ alignas(16) u16 Ps[2 * 5120];  // per-wave [ks32][32 rows][40] 10KB
  __shared__ float Ll[32];

  const int tid = threadIdx.x;
  const int w = tid >> 6;
  const int lane = tid & 63;
  const int l15 = lane & 15, quad = lane >> 4;
  const int linear = (int)blockIdx.x;
  const int bh = linear & 31;         // head-major: L2 locality
  const int qt = 63 - (linear >> 5);  // 32-row tile, big first
  const int r0 = qt * 32;
  u16* Psw = &Ps[w * 5120];

  bf16x8 aq[2][2];
#pragma unroll
  for (int mi = 0; mi < 2; ++mi)
#pragma unroll
    for (int ks = 0; ks < 2; ++ks)
      aq[mi][ks] = *(const bf16x8*)&qsw[
          ((((size_t)bh * 128 + qt * 2 + mi) * 2 + ks) * 64 + lane) * 8];

  f32x4 oacc[2][4] = {};
  float lst[8] = {0.f, 0.f, 0.f, 0.f, 0.f, 0.f, 0.f, 0.f};

  const int ktmax = qt >> 2;
  for (int kt = w; kt <= ktmax; kt += 2) {
    // Batched K-fragment loads: 16 independent 1KB reads in flight at once.
    bf16x8 kf[2][8];
#pragma unroll
    for (int ks = 0; ks < 2; ++ks)
#pragma unroll
      for (int ni = 0; ni < 8; ++ni)
        kf[ks][ni] = *(const bf16x8*)&ksw[
            ((((size_t)bh * 128 + kt * 8 + ni) * 2 + ks) * 64 + lane) * 8];

    // S = Q K^T (scale pre-folded into Q)
    f32x4 sacc[2][8] = {};
#pragma unroll
    for (int ks = 0; ks < 2; ++ks)
#pragma unroll
      for (int ni = 0; ni < 8; ++ni) {
        sacc[0][ni] = mfma16(aq[0][ks], kf[ks][ni], sacc[0][ni]);
        sacc[1][ni] = mfma16(aq[1][ks], kf[ks][ni], sacc[1][ni]);
      }

    // Batched V-fragment loads: issued now so their L2 latency is covered by
    // the entire softmax phase below.
    bf16x8 vf[4][4];
#pragma unroll
    for (int ks = 0; ks < 4; ++ks)
#pragma unroll
      for (int ni = 0; ni < 4; ++ni)
        vf[ks][ni] = *(const bf16x8*)&vsw[
            (((size_t)bh * 64 + kt * 4 + ks) * 4 + ni) * 512 + lane * 8];

    const bool diag = (kt == ktmax);
    const int k0 = kt * 128;
#pragma unroll
    for (int mi = 0; mi < 2; ++mi)
#pragma unroll
      for (int r = 0; r < 4; ++r) {
        const int prow = mi * 16 + quad * 4 + r;
        float sv[8];
#pragma unroll
        for (int ni = 0; ni < 8; ++ni) sv[ni] = sacc[mi][ni][r];
        if (diag) {
#pragma unroll
          for (int ni = 0; ni < 8; ++ni)
            if (k0 + ni * 16 + l15 > r0 + prow) sv[ni] = -__builtin_inff();
        }
        float rs = 0.f;
#pragma unroll
        for (int ni = 0; ni < 8; ++ni) {
          float p = __expf(sv[ni]);
          sv[ni] = p;
          rs += p;
        }
        lst[mi * 4 + r] += rsum16(rs);
#pragma unroll
        for (int ni = 0; ni < 8; ++ni)
          Psw[(ni >> 1) * 1280 + prow * 40 + (ni & 1) * 16 + l15] = f2b(sv[ni]);
      }

    // Wave-private LDS RAW: pin source order (TBAA could hoist the reads).
    asm volatile("" ::: "memory");

#pragma unroll
    for (int ks = 0; ks < 4; ++ks) {
      bf16x8 ap0 = *(const bf16x8*)&Psw[ks * 1280 + l15 * 40 + quad * 8];
      bf16x8 ap1 = *(const bf16x8*)&Psw[ks * 1280 + (16 + l15) * 40 + quad * 8];
#pragma unroll
      for (int ni = 0; ni < 4; ++ni) {
        oacc[0][ni] = mfma16(ap0, vf[ks][ni], oacc[0][ni]);
        oacc[1][ni] = mfma16(ap1, vf[ks][ni], oacc[1][ni]);
      }
    }
  }

  // Static-max merge: partial (O, l) just add. Wave1 publishes via its own
  // (now dead) Ps region; __syncthreads orders the cross-type LDS reuse.
  float* Of = (float*)&Ps[5120];  // 8KB needed, 10KB available
  if (w == 1) {
#pragma unroll
    for (int mi = 0; mi < 2; ++mi)
#pragma unroll
      for (int r = 0; r < 4; ++r) {
        const int row = mi * 16 + quad * 4 + r;
        if (l15 == 0) Ll[row] = lst[mi * 4 + r];
#pragma unroll
        for (int ni = 0; ni < 4; ++ni)
          Of[row * 64 + ni * 16 + l15] = oacc[mi][ni][r];
      }
  }
  __syncthreads();
  if (w == 0) {
    const int b = bh >> 4, h = bh & 15;
#pragma unroll
    for (int mi = 0; mi < 2; ++mi)
#pragma unroll
      for (int r = 0; r < 4; ++r) {
        const int row = mi * 16 + quad * 4 + r;
        const float rl = 1.0f / (lst[mi * 4 + r] + Ll[row]);
        const int trow = r0 + row;
#pragma unroll
        for (int ni = 0; ni < 4; ++ni) {
          float o = oacc[mi][ni][r] + Of[row * 64 + ni * 16 + l15];
          attn[((size_t)b * NT + trow) * ND + h * HD + ni * 16 + l15] = f2b(o * rl);
        }
      }
  }
}

extern "C" void kernel_launch(void* const* d_in, const int* in_sizes, int n_in,
                              void* d_out, int out_size, void* d_ws, size_t ws_size,
                              hipStream_t stream) {
  const float* x = (const float*)d_in[0];      // (B,T,D) f32
  const float* qkv_w = (const float*)d_in[1];  // (D,3D) f32
  const float* qkv_b = (const float*)d_in[2];  // (3D,) f32
  const float* out_w = (const float*)d_in[3];  // (D,D) f32
  const float* out_b = (const float*)d_in[4];  // (D,) f32
  float* out = (float*)d_out;

  u16* ws = (u16*)d_ws;
  u16* xb    = ws;                          // 4096*1024
  u16* wqkvT = xb + (size_t)4096 * 1024;    // 3072*1024
  u16* woutT = wqkvT + 3072 * 1024;         // 1024*1024
  u16* qkv   = woutT + 1024 * 1024;         // 4096*3072
  u16* qsw   = qkv + (size_t)4096 * 3072;   // 32*2048*64
  u16* ksw   = qsw + (size_t)32 * 2048 * 64;
  u16* vsw   = ksw + (size_t)32 * 2048 * 64;
  u16* attn  = vsw + (size_t)32 * 2048 * 64; // 4096*1024

  cast_f32_bf16<<<(NB * NT * ND) / (256 * 8), 256, 0, stream>>>(
      x, xb, NB * NT * ND);

  transpose_cast<<<dim3(3 * ND / 32, ND / 32), dim3(32, 8), 0, stream>>>(
      qkv_w, wqkvT, ND, 3 * ND);
  transpose_cast<<<dim3(ND / 32, ND / 32), dim3(32, 8), 0, stream>>>(
      out_w, woutT, ND, ND);

  gemm_bt<128, false><<<dim3(3 * ND / 128, NB * NT / 128), 256, 0, stream>>>(
      xb, wqkvT, qkv_b, qkv, NB * NT, 3 * ND, ND);

  prep_frag<<<dim3(NT / 32, NB * NH), 256, 0, stream>>>(qkv, qsw, ksw, vsw);

  flash_kernel<<<dim3(2048), 128, 0, stream>>>(qsw, ksw, vsw, attn);

  gemm_bt<64, true><<<dim3(ND / 128, NB * NT / 64), 256, 0, stream>>>(
      attn, woutT, out_b, out, NB * NT, ND, ND);
}